// Round 1
// baseline (194.032 us; speedup 1.0000x reference)
//
#include <hip/hip_runtime.h>
#include <hip/hip_bf16.h>
#include <stdint.h>

#define N    8192
#define D    256
#define NCLS 100

static constexpr float TEMP    = 0.5f;
// sqrt(log2(e)/TEMP): fold exp->exp2 conversion and 1/TEMP into both operands
static constexpr float SCALE_F = 1.69864360f;
static constexpr float E2      = 7.38905609893065f;  // exp(1/TEMP)

typedef __bf16 bf16x8 __attribute__((ext_vector_type(8)));
typedef float  f32x4  __attribute__((ext_vector_type(4)));

__device__ __forceinline__ unsigned short f2bf(float f) {
  union { float f; unsigned int u; } x; x.f = f;
  unsigned int r = x.u + 0x7fffu + ((x.u >> 16) & 1u);  // RNE
  return (unsigned short)(r >> 16);
}

__device__ __forceinline__ void gld16(const void* g, void* l) {
  __builtin_amdgcn_global_load_lds(
      (const __attribute__((address_space(1))) unsigned int*)g,
      (__attribute__((address_space(3))) unsigned int*)l, 16, 0, 0);
}

// ---------------- Kernel A: row-normalize, write scaled bf16, class sums ----
__global__ __launch_bounds__(256) void normalize_kernel(
    const float* __restrict__ emb, const long long* __restrict__ label,
    unsigned short* __restrict__ abf, float* __restrict__ S,
    int* __restrict__ cnt) {
  const int row  = blockIdx.x * 4 + (threadIdx.x >> 6);
  const int lane = threadIdx.x & 63;
  const float4 v = ((const float4*)(emb + (size_t)row * D))[lane];
  float ss = v.x * v.x + v.y * v.y + v.z * v.z + v.w * v.w;
#pragma unroll
  for (int off = 1; off < 64; off <<= 1) ss += __shfl_xor(ss, off);
  const float rn = rsqrtf(ss);
  const float4 nv = {v.x * rn, v.y * rn, v.z * rn, v.w * rn};

  ushort4 o;
  o.x = f2bf(nv.x * SCALE_F); o.y = f2bf(nv.y * SCALE_F);
  o.z = f2bf(nv.z * SCALE_F); o.w = f2bf(nv.w * SCALE_F);
  ((ushort4*)(abf + (size_t)row * D))[lane] = o;

  const int c = (int)label[row];
  float* Sc = S + c * D + lane * 4;
  atomicAdd(Sc + 0, nv.x); atomicAdd(Sc + 1, nv.y);
  atomicAdd(Sc + 2, nv.z); atomicAdd(Sc + 3, nv.w);
  if (lane == 0) atomicAdd(cnt + c, 1);
}

// ---------------- Kernel B: rowsum_i += sum_j exp2(Â_i · Â_j) ---------------
#define TM 128
#define TN 128
#define BK 64
#define JT 4  // j-tiles per block

__global__ __launch_bounds__(256) void simexp_rowsum_kernel(
    const unsigned short* __restrict__ A, float* __restrict__ rowsum) {
  __shared__ __align__(16) unsigned short sa[TM * BK];
  __shared__ __align__(16) unsigned short sb[TN * BK];

  const int tid  = threadIdx.x;
  const int w    = tid >> 6;
  const int lane = tid & 63;
  const int quad = lane >> 4;
  const int l15  = lane & 15;
  const int row0 = blockIdx.y * TM;
  const int jc0  = blockIdx.x * (TN * JT);
  const int wm   = (w & 1) * 64;
  const int wn   = (w >> 1) * 64;

  // global-load lane addressing for staging: 8 lanes per 64-col row
  const int srow = lane >> 3;        // 0..7
  const int scol = (lane & 7) * 8;   // element offset, 16B per lane

  float rowpart[4][4];  // [mt][reg] row partial sums (exp2 accumulation)
#pragma unroll
  for (int mt = 0; mt < 4; ++mt)
#pragma unroll
    for (int e = 0; e < 4; ++e) rowpart[mt][e] = 0.f;

  for (int jt = 0; jt < JT; ++jt) {
    const int jbase = jc0 + jt * TN;
    f32x4 acc[4][4];
#pragma unroll
    for (int mt = 0; mt < 4; ++mt)
#pragma unroll
      for (int nt = 0; nt < 4; ++nt) acc[mt][nt] = (f32x4){0.f, 0.f, 0.f, 0.f};

    for (int kc = 0; kc < D; kc += BK) {
      // stage A (128x64) and B (128x64) chunks, async direct-to-LDS
#pragma unroll
      for (int p = 0; p < 4; ++p) {
        const int seg = p * 4 + w;                  // wave-uniform
        const int r   = seg * 8 + srow;             // tile-row this lane loads
        gld16(A + (size_t)(row0 + r) * D + kc + scol, sa + seg * 512);
        gld16(A + (size_t)(jbase + r) * D + kc + scol, sb + seg * 512);
      }
      __syncthreads();

#pragma unroll
      for (int kk = 0; kk < BK; kk += 32) {
        const int ko = kk + quad * 8;
        bf16x8 af[4], bfr[4];
#pragma unroll
        for (int mt = 0; mt < 4; ++mt)
          af[mt] = *(const bf16x8*)(sa + (wm + mt * 16 + l15) * BK + ko);
#pragma unroll
        for (int nt = 0; nt < 4; ++nt)
          bfr[nt] = *(const bf16x8*)(sb + (wn + nt * 16 + l15) * BK + ko);
#pragma unroll
        for (int mt = 0; mt < 4; ++mt)
#pragma unroll
          for (int nt = 0; nt < 4; ++nt)
            acc[mt][nt] = __builtin_amdgcn_mfma_f32_16x16x32_bf16(
                af[mt], bfr[nt], acc[mt][nt], 0, 0, 0);
      }
      __syncthreads();
    }

    // epilogue: exp2 of every sim element, accumulate into row partials
#pragma unroll
    for (int mt = 0; mt < 4; ++mt)
#pragma unroll
      for (int nt = 0; nt < 4; ++nt)
#pragma unroll
        for (int e = 0; e < 4; ++e)
          rowpart[mt][e] += __builtin_amdgcn_exp2f(acc[mt][nt][e]);
  }

  // reduce across the 16 lanes sharing a quad (C layout: col=lane&15,
  // row=quad*4+reg), then one atomic per row per block
#pragma unroll
  for (int mt = 0; mt < 4; ++mt)
#pragma unroll
    for (int e = 0; e < 4; ++e) {
      float v = rowpart[mt][e];
      v += __shfl_xor(v, 1);
      v += __shfl_xor(v, 2);
      v += __shfl_xor(v, 4);
      v += __shfl_xor(v, 8);
      if (l15 == 0)
        atomicAdd(&rowsum[row0 + wm + mt * 16 + quad * 4 + e], v);
    }
}

// ---------------- Kernel C: loss = sum log(rs_i - e^2) - class term ---------
__global__ __launch_bounds__(256) void finalize_kernel(
    const float* __restrict__ rowsum, const long long* __restrict__ label,
    const int* __restrict__ cnt, const float* __restrict__ S,
    float* __restrict__ out) {
  __shared__ float red[256];
  const int tid = threadIdx.x;
  float acc = 0.f;
  for (int i = tid; i < N; i += 256) {
    const int c = (int)label[i];
    if (cnt[c] > 1) acc += logf(rowsum[i] - E2);
  }
  if (tid < NCLS) {
    const int m = cnt[tid];
    if (m > 1) {
      float ss = 0.f;
      const float* Sc = S + tid * D;
      for (int k = 0; k < D; ++k) { const float v = Sc[k]; ss += v * v; }
      acc -= (ss - (float)m) / (TEMP * (float)(m - 1));
    }
  }
  red[tid] = acc;
  __syncthreads();
  for (int s = 128; s > 0; s >>= 1) {
    if (tid < s) red[tid] += red[tid + s];
    __syncthreads();
  }
  if (tid == 0) out[0] = red[0];
}

// ---------------------------------------------------------------------------
extern "C" void kernel_launch(void* const* d_in, const int* in_sizes, int n_in,
                              void* d_out, int out_size, void* d_ws,
                              size_t ws_size, hipStream_t stream) {
  const float* emb = (const float*)d_in[0];
  const long long* label = (const long long*)d_in[1];
  float* out = (float*)d_out;

  char* ws = (char*)d_ws;
  unsigned short* abf = (unsigned short*)ws;            // N*D bf16 = 4 MB
  float* rowsum = (float*)(ws + (size_t)N * D * 2);     // N floats
  float* S = rowsum + N;                                // NCLS*D floats
  int* cnt = (int*)(S + NCLS * D);                      // NCLS ints

  const size_t zbytes = (size_t)N * 4 + (size_t)NCLS * D * 4 + NCLS * 4;
  hipMemsetAsync(rowsum, 0, zbytes, stream);

  normalize_kernel<<<N / 4, 256, 0, stream>>>(emb, label, abf, S, cnt);

  dim3 gridB(N / (TN * JT), N / TM);  // (16, 64)
  simexp_rowsum_kernel<<<gridB, 256, 0, stream>>>(abf, rowsum);

  finalize_kernel<<<1, 256, 0, stream>>>(rowsum, label, cnt, S, out);
}

// Round 2
// 134.566 us; speedup vs baseline: 1.4419x; 1.4419x over previous
//
#include <hip/hip_runtime.h>
#include <hip/hip_bf16.h>
#include <stdint.h>

#define N    8192
#define D    256
#define NCLS 100

static constexpr float TEMP    = 0.5f;
static constexpr float SCALE_F = 1.69864360f;  // sqrt(log2e/TEMP)
static constexpr float E2      = 7.38905609893065f;
static constexpr float LN2     = 0.69314718055994531f;

typedef __bf16 bf16x8 __attribute__((ext_vector_type(8)));
typedef float  f32x4  __attribute__((ext_vector_type(4)));

__device__ __forceinline__ unsigned short f2bf(float f) {
  union { float f; unsigned int u; } x; x.f = f;
  unsigned int r = x.u + 0x7fffu + ((x.u >> 16) & 1u);
  return (unsigned short)(r >> 16);
}
__device__ __forceinline__ float bf2f(unsigned short b) {
  union { unsigned int u; float f; } x; x.u = ((unsigned int)b) << 16;
  return x.f;
}
__device__ __forceinline__ void gld16(const void* g, void* l) {
  __builtin_amdgcn_global_load_lds(
      (const __attribute__((address_space(1))) unsigned int*)g,
      (__attribute__((address_space(3))) unsigned int*)l, 16, 0, 0);
}

__global__ __launch_bounds__(256) void normalize_kernel(
    const float* __restrict__ emb, const long long* __restrict__ label,
    unsigned short* __restrict__ abf, int* __restrict__ cnt,
    int* __restrict__ list) {
  const int row  = blockIdx.x * 4 + (threadIdx.x >> 6);
  const int lane = threadIdx.x & 63;
  const float4 v = ((const float4*)(emb + (size_t)row * D))[lane];
  float ss = v.x * v.x + v.y * v.y + v.z * v.z + v.w * v.w;
#pragma unroll
  for (int off = 1; off < 64; off <<= 1) ss += __shfl_xor(ss, off);
  const float s = rsqrtf(ss) * SCALE_F;
  ushort4 o;
  o.x = f2bf(v.x * s); o.y = f2bf(v.y * s);
  o.z = f2bf(v.z * s); o.w = f2bf(v.w * s);
  ((ushort4*)(abf + (size_t)row * D))[lane] = o;
  if (lane == 0) {
    const int c = (int)label[row];
    const int slot = atomicAdd(cnt + c, 1);
    list[c * 256 + slot] = row;
  }
}

#define TM 128
#define TN 128
#define BK 64
#define JT 4

__global__ __launch_bounds__(256) void simexp_rowsum_kernel(
    const unsigned short* __restrict__ A, float* __restrict__ rowsum) {
  __shared__ __align__(16) unsigned short sa[TM * BK];
  __shared__ __align__(16) unsigned short sb[TN * BK];
  const int tid  = threadIdx.x;
  const int w    = tid >> 6;
  const int lane = tid & 63;
  const int quad = lane >> 4;
  const int l15  = lane & 15;
  const int row0 = blockIdx.y * TM;
  const int jc0  = blockIdx.x * (TN * JT);
  const int wm   = (w & 1) * 64;
  const int wn   = (w >> 1) * 64;
  const int srow = lane >> 3;
  const int scol = (((lane & 7) ^ srow) << 3);  // XOR-swizzled source block

  float rowpart[4][4];
#pragma unroll
  for (int mt = 0; mt < 4; ++mt)
#pragma unroll
    for (int e = 0; e < 4; ++e) rowpart[mt][e] = 0.f;

  for (int jt = 0; jt < JT; ++jt) {
    const int jbase = jc0 + jt * TN;
    f32x4 acc[4][4];
#pragma unroll
    for (int mt = 0; mt < 4; ++mt)
#pragma unroll
      for (int nt = 0; nt < 4; ++nt) acc[mt][nt] = (f32x4){0.f, 0.f, 0.f, 0.f};

    for (int kc = 0; kc < D; kc += BK) {
#pragma unroll
      for (int p = 0; p < 4; ++p) {
        const int seg = p * 4 + w;
        const int r   = seg * 8 + srow;
        gld16(A + (size_t)(row0 + r) * D + kc + scol, sa + seg * 512);
        gld16(A + (size_t)(jbase + r) * D + kc + scol, sb + seg * 512);
      }
      __syncthreads();
#pragma unroll
      for (int kk = 0; kk < BK; kk += 32) {
        const int kb = (kk >> 3) + quad;
        const int sw = ((kb ^ (l15 & 7)) << 3);
        bf16x8 af[4], bfr[4];
#pragma unroll
        for (int mt = 0; mt < 4; ++mt)
          af[mt] = *(const bf16x8*)(sa + ((wm + mt * 16 + l15) << 6) + sw);
#pragma unroll
        for (int nt = 0; nt < 4; ++nt)
          bfr[nt] = *(const bf16x8*)(sb + ((wn + nt * 16 + l15) << 6) + sw);
#pragma unroll
        for (int mt = 0; mt < 4; ++mt)
#pragma unroll
          for (int nt = 0; nt < 4; ++nt)
            acc[mt][nt] = __builtin_amdgcn_mfma_f32_16x16x32_bf16(
                af[mt], bfr[nt], acc[mt][nt], 0, 0, 0);
      }
      __syncthreads();
    }
#pragma unroll
    for (int mt = 0; mt < 4; ++mt)
#pragma unroll
      for (int nt = 0; nt < 4; ++nt)
#pragma unroll
        for (int e = 0; e < 4; ++e)
          rowpart[mt][e] += __builtin_amdgcn_exp2f(acc[mt][nt][e]);
  }
#pragma unroll
  for (int mt = 0; mt < 4; ++mt)
#pragma unroll
    for (int e = 0; e < 4; ++e) {
      float v = rowpart[mt][e];
      v += __shfl_xor(v, 1);
      v += __shfl_xor(v, 2);
      v += __shfl_xor(v, 4);
      v += __shfl_xor(v, 8);
      if (l15 == 0)
        atomicAdd(&rowsum[row0 + wm + mt * 16 + quad * 4 + e], v);
    }
}

__global__ __launch_bounds__(256) void finalize_kernel(
    const unsigned short* __restrict__ abf, const float* __restrict__ rowsum,
    const long long* __restrict__ label, const int* __restrict__ cnt,
    const int* __restrict__ list, float* __restrict__ out) {
  __shared__ float red[4];
  __shared__ int rows_l[256];
  const int tid  = threadIdx.x;
  const int w    = tid >> 6;
  const int lane = tid & 63;

  if (blockIdx.x < NCLS) {
    const int c = blockIdx.x;
    const int m = cnt[c];
    if (m <= 1) return;
    if (tid < m) rows_l[tid] = list[c * 256 + tid];
    __syncthreads();
    float acc = 0.f;
    for (int s = 0; s < m; ++s)
      acc += bf2f(abf[(size_t)rows_l[s] * D + tid]);
    float v = acc * acc;
#pragma unroll
    for (int off = 1; off < 64; off <<= 1) v += __shfl_xor(v, off);
    if (lane == 0) red[w] = v;
    __syncthreads();
    if (tid == 0) {
      const float ssq = red[0] + red[1] + red[2] + red[3];
      const float term = (ssq * LN2 - 2.0f * (float)m) / (float)(m - 1);
      atomicAdd(out, -term);
    }
  } else {
    const int i = (blockIdx.x - NCLS) * 256 + tid;
    const int c = (int)label[i];
    float v = 0.f;
    if (cnt[c] > 1)
      v = __builtin_amdgcn_logf(rowsum[i] - E2) * LN2;
#pragma unroll
    for (int off = 1; off < 64; off <<= 1) v += __shfl_xor(v, off);
    if (lane == 0) red[w] = v;
    __syncthreads();
    if (tid == 0)
      atomicAdd(out, red[0] + red[1] + red[2] + red[3]);
  }
}

extern "C" void kernel_launch(void* const* d_in, const int* in_sizes, int n_in,
                              void* d_out, int out_size, void* d_ws,
                              size_t ws_size, hipStream_t stream) {
  const float* emb = (const float*)d_in[0];
  const long long* label = (const long long*)d_in[1];
  float* out = (float*)d_out;

  char* ws = (char*)d_ws;
  unsigned short* abf = (unsigned short*)ws;           // 4 MB
  float* rowsum = (float*)(ws + (size_t)N * D * 2);    // N floats
  int* cnt = (int*)(rowsum + N);                       // 128 ints (100 used)
  int* list = cnt + 128;                               // NCLS*256 ints

  hipMemsetAsync(rowsum, 0, (size_t)N * 4 + 128 * 4, stream);
  hipMemsetAsync(out, 0, sizeof(float), stream);

  normalize_kernel<<<N / 4, 256, 0, stream>>>(emb, label, abf, cnt, list);
  dim3 gridB(N / (TN * JT), N / TM);
  simexp_rowsum_kernel<<<gridB, 256, 0, stream>>>(abf, rowsum);
  finalize_kernel<<<NCLS + N / 256, 256, 0, stream>>>(abf, rowsum, label, cnt,
                                                      list, out);
}

// Round 3
// 134.036 us; speedup vs baseline: 1.4476x; 1.0040x over previous
//
#include <hip/hip_runtime.h>
#include <hip/hip_bf16.h>
#include <stdint.h>

#define N    8192
#define D    256
#define NCLS 100

static constexpr float TEMP    = 0.5f;
static constexpr float SCALE_F = 1.69864360f;  // sqrt(log2e/TEMP)
static constexpr float E2      = 7.38905609893065f;
static constexpr float LN2     = 0.69314718055994531f;

typedef __bf16 bf16x8 __attribute__((ext_vector_type(8)));
typedef float  f32x4  __attribute__((ext_vector_type(4)));

__device__ __forceinline__ unsigned short f2bf(float f) {
  union { float f; unsigned int u; } x; x.f = f;
  unsigned int r = x.u + 0x7fffu + ((x.u >> 16) & 1u);
  return (unsigned short)(r >> 16);
}
__device__ __forceinline__ float bf2f(unsigned short b) {
  union { unsigned int u; float f; } x; x.u = ((unsigned int)b) << 16;
  return x.f;
}
__device__ __forceinline__ void gld16(const void* g, void* l) {
  __builtin_amdgcn_global_load_lds(
      (const __attribute__((address_space(1))) unsigned int*)g,
      (__attribute__((address_space(3))) unsigned int*)l, 16, 0, 0);
}

__global__ __launch_bounds__(256) void normalize_kernel(
    const float* __restrict__ emb, const long long* __restrict__ label,
    unsigned short* __restrict__ abf, int* __restrict__ cnt,
    int* __restrict__ list) {
  const int row  = blockIdx.x * 4 + (threadIdx.x >> 6);
  const int lane = threadIdx.x & 63;
  const float4 v = ((const float4*)(emb + (size_t)row * D))[lane];
  float ss = v.x * v.x + v.y * v.y + v.z * v.z + v.w * v.w;
#pragma unroll
  for (int off = 1; off < 64; off <<= 1) ss += __shfl_xor(ss, off);
  const float s = rsqrtf(ss) * SCALE_F;
  ushort4 o;
  o.x = f2bf(v.x * s); o.y = f2bf(v.y * s);
  o.z = f2bf(v.z * s); o.w = f2bf(v.w * s);
  ((ushort4*)(abf + (size_t)row * D))[lane] = o;
  if (lane == 0) {
    const int c = (int)label[row];
    const int slot = atomicAdd(cnt + c, 1);
    list[c * 256 + slot] = row;
  }
}

// ---- Kernel B: upper-triangle tiles only; off-diag tiles feed both the row
// ---- sums (rows) and, via symmetry, the column sums (transposed rows).
#define TM 128
#define TN 128
#define BK 64
#define JT 2  // j-tiles per super-tile

// blocks before row-block bi: off(bi) = 32*bi - q*(q-1+r), q=bi>>1, r=bi&1
__device__ __forceinline__ int tri_off(int bi) {
  const int q = bi >> 1, r = bi & 1;
  return 32 * bi - q * (q - 1 + r);
}

__global__ __launch_bounds__(256) void simexp_rowsum_kernel(
    const unsigned short* __restrict__ A, float* __restrict__ rowsum) {
  __shared__ __align__(16) unsigned short sa[TM * BK];
  __shared__ __align__(16) unsigned short sb[TN * BK];
  const int tid  = threadIdx.x;
  const int w    = tid >> 6;
  const int lane = tid & 63;
  const int quad = lane >> 4;
  const int l15  = lane & 15;

  // invert linear block id -> (bi, sj)
  int bi = 0;
  {
    const int id = blockIdx.x;
    while (bi < 63 && tri_off(bi + 1) <= id) ++bi;
    // sj computed below from remainder
  }
  const int sj   = (bi >> 1) + (blockIdx.x - tri_off(bi));
  const int row0 = bi * TM;
  const int jc0  = sj * (TN * JT);

  const int wm   = (w & 1) * 64;
  const int wn   = (w >> 1) * 64;
  const int srow = lane >> 3;
  const int scol = (((lane & 7) ^ srow) << 3);  // XOR-swizzled source block

  float rowpart[4][4];
#pragma unroll
  for (int mt = 0; mt < 4; ++mt)
#pragma unroll
    for (int e = 0; e < 4; ++e) rowpart[mt][e] = 0.f;

  for (int jt = 0; jt < JT; ++jt) {
    const int jbase = jc0 + jt * TN;
    if (jbase < row0) continue;          // below diagonal: handled by transpose
    const bool diag = (jbase == row0);

    f32x4 acc[4][4];
#pragma unroll
    for (int mt = 0; mt < 4; ++mt)
#pragma unroll
      for (int nt = 0; nt < 4; ++nt) acc[mt][nt] = (f32x4){0.f, 0.f, 0.f, 0.f};

    for (int kc = 0; kc < D; kc += BK) {
#pragma unroll
      for (int p = 0; p < 4; ++p) {
        const int seg = p * 4 + w;
        const int r   = seg * 8 + srow;
        gld16(A + (size_t)(row0 + r) * D + kc + scol, sa + seg * 512);
        gld16(A + (size_t)(jbase + r) * D + kc + scol, sb + seg * 512);
      }
      __syncthreads();
#pragma unroll
      for (int kk = 0; kk < BK; kk += 32) {
        const int kb = (kk >> 3) + quad;
        const int sw = ((kb ^ (l15 & 7)) << 3);
        bf16x8 af[4], bfr[4];
#pragma unroll
        for (int mt = 0; mt < 4; ++mt)
          af[mt] = *(const bf16x8*)(sa + ((wm + mt * 16 + l15) << 6) + sw);
#pragma unroll
        for (int nt = 0; nt < 4; ++nt)
          bfr[nt] = *(const bf16x8*)(sb + ((wn + nt * 16 + l15) << 6) + sw);
#pragma unroll
        for (int mt = 0; mt < 4; ++mt)
#pragma unroll
          for (int nt = 0; nt < 4; ++nt)
            acc[mt][nt] = __builtin_amdgcn_mfma_f32_16x16x32_bf16(
                af[mt], bfr[nt], acc[mt][nt], 0, 0, 0);
      }
      __syncthreads();
    }

    // epilogue: exp2 once per element; accumulate rows (regs, across jt) and
    // columns (per-tile, via symmetry -> transposed rows)
    float cs[4] = {0.f, 0.f, 0.f, 0.f};
#pragma unroll
    for (int mt = 0; mt < 4; ++mt)
#pragma unroll
      for (int nt = 0; nt < 4; ++nt)
#pragma unroll
        for (int e = 0; e < 4; ++e) {
          const float v = __builtin_amdgcn_exp2f(acc[mt][nt][e]);
          rowpart[mt][e] += v;
          cs[nt] += v;
        }
    if (!diag) {
#pragma unroll
      for (int nt = 0; nt < 4; ++nt) {
        float v = cs[nt];
        v += __shfl_xor(v, 16);
        v += __shfl_xor(v, 32);
        if (lane < 16)
          atomicAdd(&rowsum[jbase + wn + nt * 16 + lane], v);
      }
    }
  }

  // row contributions (C layout: col=lane&15, row=quad*4+reg)
#pragma unroll
  for (int mt = 0; mt < 4; ++mt)
#pragma unroll
    for (int e = 0; e < 4; ++e) {
      float v = rowpart[mt][e];
      v += __shfl_xor(v, 1);
      v += __shfl_xor(v, 2);
      v += __shfl_xor(v, 4);
      v += __shfl_xor(v, 8);
      if (l15 == 0)
        atomicAdd(&rowsum[row0 + wm + mt * 16 + quad * 4 + e], v);
    }
}

__global__ __launch_bounds__(256) void finalize_kernel(
    const unsigned short* __restrict__ abf, const float* __restrict__ rowsum,
    const long long* __restrict__ label, const int* __restrict__ cnt,
    const int* __restrict__ list, float* __restrict__ out) {
  __shared__ float red[4];
  __shared__ int rows_l[256];
  const int tid  = threadIdx.x;
  const int w    = tid >> 6;
  const int lane = tid & 63;

  if (blockIdx.x < NCLS) {
    const int c = blockIdx.x;
    const int m = cnt[c];
    if (m <= 1) return;
    if (tid < m) rows_l[tid] = list[c * 256 + tid];
    __syncthreads();
    float acc = 0.f;
    for (int s = 0; s < m; ++s)
      acc += bf2f(abf[(size_t)rows_l[s] * D + tid]);
    float v = acc * acc;
#pragma unroll
    for (int off = 1; off < 64; off <<= 1) v += __shfl_xor(v, off);
    if (lane == 0) red[w] = v;
    __syncthreads();
    if (tid == 0) {
      const float ssq = red[0] + red[1] + red[2] + red[3];
      const float term = (ssq * LN2 - 2.0f * (float)m) / (float)(m - 1);
      atomicAdd(out, -term);
    }
  } else {
    const int i = (blockIdx.x - NCLS) * 256 + tid;
    const int c = (int)label[i];
    float v = 0.f;
    if (cnt[c] > 1)
      v = __builtin_amdgcn_logf(rowsum[i] - E2) * LN2;
#pragma unroll
    for (int off = 1; off < 64; off <<= 1) v += __shfl_xor(v, off);
    if (lane == 0) red[w] = v;
    __syncthreads();
    if (tid == 0)
      atomicAdd(out, red[0] + red[1] + red[2] + red[3]);
  }
}

extern "C" void kernel_launch(void* const* d_in, const int* in_sizes, int n_in,
                              void* d_out, int out_size, void* d_ws,
                              size_t ws_size, hipStream_t stream) {
  const float* emb = (const float*)d_in[0];
  const long long* label = (const long long*)d_in[1];
  float* out = (float*)d_out;

  char* ws = (char*)d_ws;
  unsigned short* abf = (unsigned short*)ws;           // 4 MB
  float* rowsum = (float*)(ws + (size_t)N * D * 2);    // N floats
  int* cnt = (int*)(rowsum + N);                       // 128 ints (100 used)
  int* list = cnt + 128;                               // NCLS*256 ints

  hipMemsetAsync(rowsum, 0, (size_t)N * 4 + 128 * 4, stream);
  hipMemsetAsync(out, 0, sizeof(float), stream);

  normalize_kernel<<<N / 4, 256, 0, stream>>>(emb, label, abf, cnt, list);

  // upper-triangle super-tiles: sum_{bi=0}^{63} (32 - bi/2) = 1056 blocks
  simexp_rowsum_kernel<<<1056, 256, 0, stream>>>(abf, rowsum);

  finalize_kernel<<<NCLS + N / 256, 256, 0, stream>>>(abf, rowsum, label, cnt,
                                                      list, out);
}